// Round 14
// baseline (188.797 us; speedup 1.0000x reference)
//
#include <hip/hip_runtime.h>
#include <math.h>

#define BB 2
#define TT 2048
#define DD 1024
#define HH 16
#define BT (BB*TT)   // 4096
#define VD 1280      // qkv fused output width

typedef __attribute__((ext_vector_type(4))) _Float16 f16x4;
typedef __attribute__((ext_vector_type(8))) _Float16 f16x8;
typedef __attribute__((ext_vector_type(4))) float f32x4;

__device__ __forceinline__ void gload16(const void* g, void* l) {
    __builtin_amdgcn_global_load_lds((const __attribute__((address_space(1))) void*)g,
                                     (__attribute__((address_space(3))) void*)l, 16, 0, 0);
}

// ---------------- fp32 -> f16 conversion / packing -------------------------
__global__ __launch_bounds__(256) void convert_kernel(
    const float* __restrict__ x,  const float* __restrict__ W1q,
    const float* __restrict__ W2q, const float* __restrict__ W1k,
    const float* __restrict__ W2k, const float* __restrict__ Wv,
    const float* __restrict__ Wout, const float* __restrict__ bv,
    _Float16* __restrict__ xb, _Float16* __restrict__ Wqkvb,
    _Float16* __restrict__ Woutb, float* __restrict__ biasqkv) {
    int c = blockIdx.x * 256 + threadIdx.x;   // chunk of 8 elements
    if (c < 819200) {
        const float* src; _Float16* dst; int off;
        if      (c < 524288) { src = x;    dst = xb;              off = c; }
        else if (c < 532480) { src = W1q;  dst = Wqkvb;           off = c - 524288; }
        else if (c < 540672) { src = W2q;  dst = Wqkvb + 65536;   off = c - 532480; }
        else if (c < 548864) { src = W1k;  dst = Wqkvb + 131072;  off = c - 540672; }
        else if (c < 557056) { src = W2k;  dst = Wqkvb + 196608;  off = c - 548864; }
        else if (c < 688128) { src = Wv;   dst = Wqkvb + 262144;  off = c - 557056; }
        else                 { src = Wout; dst = Woutb;           off = c - 688128; }
        float4 v0 = *(const float4*)(src + (size_t)off * 8);
        float4 v1 = *(const float4*)(src + (size_t)off * 8 + 4);
        f16x8 h;
        h[0] = (_Float16)v0.x; h[1] = (_Float16)v0.y; h[2] = (_Float16)v0.z; h[3] = (_Float16)v0.w;
        h[4] = (_Float16)v1.x; h[5] = (_Float16)v1.y; h[6] = (_Float16)v1.z; h[7] = (_Float16)v1.w;
        *(f16x8*)(dst + (size_t)off * 8) = h;
    } else if (c < 819360) {
        int col0 = (c - 819200) * 8;
        #pragma unroll
        for (int i = 0; i < 8; ++i) {
            int col = col0 + i;
            biasqkv[col] = (col < 256) ? 0.f : bv[col - 256];
        }
    }
}

// ---------------- f16 MFMA GEMM: C[M,N] = A[M,K] @ W[N,K]^T + bias ---------
__global__ __launch_bounds__(256) void gemm_f16_mfma(
    const _Float16* __restrict__ A, const _Float16* __restrict__ W,
    const float* __restrict__ bias, float* __restrict__ C, int N, int K) {
    __shared__ __attribute__((aligned(16))) _Float16 As[128 * 32];
    __shared__ __attribute__((aligned(16))) _Float16 Ws[128 * 32];
    const int tid = threadIdx.x;
    const int w = tid >> 6, lane = tid & 63;
    const int la = lane >> 4, lb = lane & 15;
    const int bm = blockIdx.x * 128, bn = blockIdx.y * 128;
    const int wr = w >> 1, wc = w & 1;

    const int c0 = tid, c1 = tid + 256;
    const int r0 = c0 >> 2, kg0 = (c0 & 3) ^ ((r0 >> 1) & 3);
    const int r1 = c1 >> 2, kg1 = (c1 & 3) ^ ((r1 >> 1) & 3);
    const _Float16* Ag0 = A + (size_t)(bm + r0) * K + kg0 * 8;
    const _Float16* Ag1 = A + (size_t)(bm + r1) * K + kg1 * 8;
    const _Float16* Wg0 = W + (size_t)(bn + r0) * K + kg0 * 8;
    const _Float16* Wg1 = W + (size_t)(bn + r1) * K + kg1 * 8;
    _Float16* Al0 = &As[(w * 64) * 8];
    _Float16* Al1 = &As[(256 + w * 64) * 8];
    _Float16* Wl0 = &Ws[(w * 64) * 8];
    _Float16* Wl1 = &Ws[(256 + w * 64) * 8];

    f32x4 acc[4][4] = {};

    int aoff[4], boff[4];
    #pragma unroll
    for (int t = 0; t < 4; ++t) {
        int ra = wr * 64 + t * 16 + lb;
        aoff[t] = ra * 32 + (la ^ ((ra >> 1) & 3)) * 8;
        int rb = wc * 64 + t * 16 + lb;
        boff[t] = rb * 32 + (la ^ ((rb >> 1) & 3)) * 8;
    }

    for (int k0 = 0; k0 < K; k0 += 32) {
        gload16(Ag0 + k0, Al0);
        gload16(Ag1 + k0, Al1);
        gload16(Wg0 + k0, Wl0);
        gload16(Wg1 + k0, Wl1);
        __syncthreads();
        f16x8 af[4], bf[4];
        #pragma unroll
        for (int t = 0; t < 4; ++t) af[t] = *(const f16x8*)&As[aoff[t]];
        #pragma unroll
        for (int t = 0; t < 4; ++t) bf[t] = *(const f16x8*)&Ws[boff[t]];
        #pragma unroll
        for (int mt = 0; mt < 4; ++mt)
            #pragma unroll
            for (int nt = 0; nt < 4; ++nt)
                acc[mt][nt] = __builtin_amdgcn_mfma_f32_16x16x32_f16(
                    af[mt], bf[nt], acc[mt][nt], 0, 0, 0);
        __syncthreads();
    }

    #pragma unroll
    for (int nt = 0; nt < 4; ++nt) {
        int col = bn + wc * 64 + nt * 16 + lb;
        float bval = bias ? bias[col] : 0.f;
        #pragma unroll
        for (int mt = 0; mt < 4; ++mt) {
            int row = bm + wr * 64 + mt * 16 + la * 4;
            #pragma unroll
            for (int i = 0; i < 4; ++i)
                C[(size_t)(row + i) * N + col] = acc[mt][nt][i] + bval;
        }
    }
}

// ---------------- exterior (Plucker) --------------------------------------
// Lqh: [bh][t][16] f16 (c 6..15 zero).
// JKf: fragment-major [bh][tile(32)][n(4)][lane(64)][4] f16 -> LDS image
//      gives conflict-free ds_read_b64 at &jk[n*256 + lane*4].
__device__ __forceinline__ void ext6(const float* a, const float* b, float* L) {
    L[0] = a[0]*b[1] - a[1]*b[0];
    L[1] = a[0]*b[2] - a[2]*b[0];
    L[2] = a[0]*b[3] - a[3]*b[0];
    L[3] = a[1]*b[2] - a[2]*b[1];
    L[4] = a[1]*b[3] - a[3]*b[1];
    L[5] = a[2]*b[3] - a[3]*b[2];
}

__global__ __launch_bounds__(256) void exterior_kernel(const float* __restrict__ Cqkv,
                                                       _Float16* __restrict__ Lqh,
                                                       _Float16* __restrict__ JKf) {
    int idx = blockIdx.x * 256 + threadIdx.x;     // over BT*HH
    if (idx >= BT * HH) return;
    int bt = idx >> 4, h = idx & 15;
    int b = bt >> 11, t = bt & (TT - 1);
    int bh = b * HH + h;
    const float* row = Cqkv + (size_t)bt * VD + h * 4;
    const _Float16 Z = (_Float16)0.f;
    float a[4], bb[4], L[6];
    #pragma unroll
    for (int i = 0; i < 4; ++i) { a[i] = row[i]; bb[i] = row[64 + i]; }
    ext6(a, bb, L);
    float s = 0.f;
    #pragma unroll
    for (int c = 0; c < 6; ++c) s += L[c] * L[c];
    float inv = 1.0f / fmaxf(sqrtf(s), 1e-12f);
    size_t qbase = ((size_t)bh * TT + t) * 16;
    f16x8 lq8 = {(_Float16)(L[0]*inv), (_Float16)(L[1]*inv), (_Float16)(L[2]*inv),
                 (_Float16)(L[3]*inv), (_Float16)(L[4]*inv), (_Float16)(L[5]*inv), Z, Z};
    f16x8 zero8 = {Z, Z, Z, Z, Z, Z, Z, Z};
    *(f16x8*)(Lqh + qbase) = lq8;
    *(f16x8*)(Lqh + qbase + 8) = zero8;

    #pragma unroll
    for (int i = 0; i < 4; ++i) { a[i] = row[128 + i]; bb[i] = row[192 + i]; }
    ext6(a, bb, L);
    s = 0.f;
    #pragma unroll
    for (int c = 0; c < 6; ++c) s += L[c] * L[c];
    const float SCALE = (float)(0.40824829046386307 * 1.4426950408889634); // 6^-0.5 * log2(e)
    inv = SCALE / fmaxf(sqrtf(s), 1e-12f);
    // fragment position: tile = t>>6, n = (t&63)>>4, lbt = t&15; granule la
    int tile = t >> 6, rr = t & 63, n = rr >> 4, lbt = rr & 15;
    size_t base = (((size_t)bh * 32 + tile) * 1024) + n * 256 + lbt * 4;
    f16x4 g0 = {(_Float16)( L[5]*inv), (_Float16)(-L[4]*inv),
                (_Float16)( L[3]*inv), (_Float16)( L[2]*inv)};
    f16x4 g1 = {(_Float16)(-L[1]*inv), (_Float16)( L[0]*inv), Z, Z};
    f16x4 z4 = {Z, Z, Z, Z};
    *(f16x4*)&JKf[base]       = g0;   // la=0: c0..3
    *(f16x4*)&JKf[base + 64]  = g1;   // la=1: c4..7
    *(f16x4*)&JKf[base + 128] = z4;   // la=2
    *(f16x4*)&JKf[base + 192] = z4;   // la=3
}

// ---------------- V transpose into fragment-major PV order -----------------
// Vf: [bh][tile(32)][mn(16)][lane(64)][4] f16 where lane=la*16+lb holds
//     V[t = tile*64 + n*16 + la*4 + j][d = m*16 + lb], mn = m*4+n.
__global__ __launch_bounds__(256) void vtrans_kernel(const float* __restrict__ Cqkv,
                                                     _Float16* __restrict__ Vf) {
    __shared__ float ls[64][65];
    const int bh = blockIdx.y, b = bh >> 4, h = bh & 15;
    const int tile = blockIdx.x;
    const int t0 = tile * 64;
    const int tid = threadIdx.x;
    const int tr = tid >> 2, dg = (tid & 3) * 16;
    const float* src = Cqkv + (size_t)(b * TT + t0 + tr) * VD + 256 + h * 64 + dg;
    #pragma unroll
    for (int j = 0; j < 4; ++j) {
        float4 v = *(const float4*)(src + j * 4);
        ls[tr][dg + j*4 + 0] = v.x;
        ls[tr][dg + j*4 + 1] = v.y;
        ls[tr][dg + j*4 + 2] = v.z;
        ls[tr][dg + j*4 + 3] = v.w;
    }
    __syncthreads();
    _Float16* dst = Vf + ((size_t)bh * 32 + tile) * 4096;
    #pragma unroll
    for (int k = 0; k < 4; ++k) {
        int g = k * 256 + tid;                 // granule id 0..1023
        int mn = g >> 6, lane = g & 63;
        int m = mn >> 2, n = mn & 3;
        int la = lane >> 4, lb = lane & 15;
        int d = m * 16 + lb, tt = n * 16 + la * 4;
        f16x4 o = { (_Float16)ls[tt][d], (_Float16)ls[tt+1][d],
                    (_Float16)ls[tt+2][d], (_Float16)ls[tt+3][d] };
        *(f16x4*)&dst[(size_t)g * 4] = o;
    }
}

// ---------------- MFMA flash attention v9 ----------------------------------
// 2-wave (128-thr) blocks, 64 q per block (32 q per wave, two B-frags).
// The 64-key tile is staged ONCE per block (each wave issues 5 gload16 into
// a SHARED static LDS buffer), double-buffered smA/smB with raw s_barrier +
// counted s_waitcnt vmcnt(5): next tile's loads stay in flight under compute.
// Static buffer names -> all LDS/M0 addresses are compile-time constants.
// p = exp2(s') directly (scores bounded by 6^-0.5, no online max).
__global__ __launch_bounds__(128) void flash_mfma_kernel(
    const _Float16* __restrict__ Lqh, const _Float16* __restrict__ JKf,
    const _Float16* __restrict__ Vf, _Float16* __restrict__ O) {
    const int id = blockIdx.x;                       // 0..1023
    const int bh = (id & 7) * 4 + ((id >> 3) & 3);   // 4 bh per XCD slot
    const int strip = 31 - (id >> 5);                // heavy first (LPT)
    const int b = bh >> 4, h = bh & 15;
    const int tid = threadIdx.x;
    const int w = tid >> 6, lane = tid & 63;
    const int la = lane >> 4, lb = lane & 15;
    const int qw = strip * 64 + w * 32;              // wave's 32 q rows
    const int q0l = qw + lb, q1l = qw + 16 + lb;

    __shared__ __attribute__((aligned(16))) _Float16 smA[5120];  // 10 KB
    __shared__ __attribute__((aligned(16))) _Float16 smB[5120];  // 10 KB

    // B-frags: blq*[j] = Lq[q][k=la*4+j]; k>=6 stored zero
    f16x4 blq0 = *(const f16x4*)(Lqh + ((size_t)bh * TT + qw + lb) * 16 + la * 4);
    f16x4 blq1 = *(const f16x4*)(Lqh + ((size_t)bh * TT + qw + 16 + lb) * 16 + la * 4);

    f32x4 acc0[4] = {}, acc1[4] = {};
    f32x4 lsv0 = {0.f, 0.f, 0.f, 0.f}, lsv1 = {0.f, 0.f, 0.f, 0.f};

    const _Float16* jbase = JKf + ((size_t)bh * 32) * 1024 + lane * 8;  // 16B/lane
    const _Float16* vbase = Vf  + ((size_t)bh * 32) * 4096 + lane * 8;
    const int nt = strip + 1;                        // tiles this block needs

    // wave 0 stages jk(2KB) + v chunks 0..2; wave 1 stages v chunks 3..7
#define STAGE(t, S) { \
    const _Float16* jp = jbase + (size_t)(t) * 1024; \
    const _Float16* vp = vbase + (size_t)(t) * 4096; \
    if (w == 0) { \
        gload16(jp,        (S)); \
        gload16(jp + 512,  (S) + 512); \
        gload16(vp,        (S) + 1024); \
        gload16(vp + 512,  (S) + 1536); \
        gload16(vp + 1024, (S) + 2048); \
    } else { \
        gload16(vp + 1536, (S) + 2560); \
        gload16(vp + 2048, (S) + 3072); \
        gload16(vp + 2560, (S) + 3584); \
        gload16(vp + 3072, (S) + 4096); \
        gload16(vp + 3584, (S) + 4608); \
    } }

#define COMPT(t, S) { \
    const int kt = (t) * 64; \
    const _Float16* jk = (S); \
    const _Float16* vt = (S) + 1024; \
    _Pragma("unroll") \
    for (int n = 0; n < 4; ++n) { \
        const int kbase = kt + n * 16; \
        if (kbase > qw + 31) break; \
        f16x4 ajk = *(const f16x4*)&jk[n * 256 + lane * 4]; \
        const bool act0 = (kbase <= qw + 15); \
        const f32x4 z = {0.f, 0.f, 0.f, 0.f}; \
        f16x4 pt0, pt1; \
        if (act0) { \
            f32x4 st = __builtin_amdgcn_mfma_f32_16x16x16f16(ajk, blq0, z, 0, 0, 0); \
            const bool needm = (kbase + 15 > qw); \
            _Pragma("unroll") \
            for (int i = 0; i < 4; ++i) { \
                float p = exp2f(st[i]); \
                if (needm) { int key = kbase + la * 4 + i; \
                             p = (key <= q0l) ? p : 0.f; } \
                lsv0[i] += p; \
                pt0[i] = (_Float16)p; } \
        } \
        { \
            f32x4 st = __builtin_amdgcn_mfma_f32_16x16x16f16(ajk, blq1, z, 0, 0, 0); \
            const bool needm = (kbase + 15 > qw + 16); \
            _Pragma("unroll") \
            for (int i = 0; i < 4; ++i) { \
                float p = exp2f(st[i]); \
                if (needm) { int key = kbase + la * 4 + i; \
                             p = (key <= q1l) ? p : 0.f; } \
                lsv1[i] += p; \
                pt1[i] = (_Float16)p; } \
        } \
        _Pragma("unroll") \
        for (int m = 0; m < 4; ++m) { \
            f16x4 av = *(const f16x4*)&vt[(m * 4 + n) * 256 + lane * 4]; \
            if (act0) acc0[m] = __builtin_amdgcn_mfma_f32_16x16x16f16(av, pt0, acc0[m], 0, 0, 0); \
            acc1[m] = __builtin_amdgcn_mfma_f32_16x16x16f16(av, pt1, acc1[m], 0, 0, 0); \
        } \
    } }

    STAGE(0, smA);
    for (int t = 0; ; t += 2) {
        // ---- even tile: compute smA, prefetch into smB
        if (t + 1 < nt) {
            STAGE(t + 1, smB);
            asm volatile("s_waitcnt vmcnt(5)" ::: "memory");
        } else {
            asm volatile("s_waitcnt vmcnt(0)" ::: "memory");
        }
        __builtin_amdgcn_sched_barrier(0);
        __builtin_amdgcn_s_barrier();          // all waves' tile-t loads done
        COMPT(t, smA);
        __builtin_amdgcn_sched_barrier(0);
        __builtin_amdgcn_s_barrier();          // all waves done reading smA
        if (t + 1 >= nt) break;
        // ---- odd tile: compute smB, prefetch into smA
        if (t + 2 < nt) {
            STAGE(t + 2, smA);
            asm volatile("s_waitcnt vmcnt(5)" ::: "memory");
        } else {
            asm volatile("s_waitcnt vmcnt(0)" ::: "memory");
        }
        __builtin_amdgcn_sched_barrier(0);
        __builtin_amdgcn_s_barrier();
        COMPT(t + 1, smB);
        __builtin_amdgcn_sched_barrier(0);
        __builtin_amdgcn_s_barrier();
        if (t + 2 >= nt) break;
    }
#undef STAGE
#undef COMPT

    // reduce lsum across the 4 la-groups holding the same q column
    float lsum0 = lsv0[0] + lsv0[1] + lsv0[2] + lsv0[3];
    float lsum1 = lsv1[0] + lsv1[1] + lsv1[2] + lsv1[3];
    lsum0 += __shfl_xor(lsum0, 16);
    lsum0 += __shfl_xor(lsum0, 32);
    lsum1 += __shfl_xor(lsum1, 16);
    lsum1 += __shfl_xor(lsum1, 32);
    const float inv0 = 1.f / lsum0, inv1 = 1.f / lsum1;
    #pragma unroll
    for (int m = 0; m < 4; ++m) {
        f16x4 o0 = { (_Float16)(acc0[m][0] * inv0), (_Float16)(acc0[m][1] * inv0),
                     (_Float16)(acc0[m][2] * inv0), (_Float16)(acc0[m][3] * inv0) };
        *(f16x4*)&O[(size_t)(b * TT + q0l) * DD + h * 64 + m * 16 + la * 4] = o0;
        f16x4 o1 = { (_Float16)(acc1[m][0] * inv1), (_Float16)(acc1[m][1] * inv1),
                     (_Float16)(acc1[m][2] * inv1), (_Float16)(acc1[m][3] * inv1) };
        *(f16x4*)&O[(size_t)(b * TT + q1l) * DD + h * 64 + m * 16 + la * 4] = o1;
    }
}

extern "C" void kernel_launch(void* const* d_in, const int* in_sizes, int n_in,
                              void* d_out, int out_size, void* d_ws, size_t ws_size,
                              hipStream_t stream) {
    const float* x    = (const float*)d_in[0];
    const float* W1q  = (const float*)d_in[1];
    const float* W2q  = (const float*)d_in[2];
    const float* W1k  = (const float*)d_in[3];
    const float* W2k  = (const float*)d_in[4];
    const float* Wv   = (const float*)d_in[5];
    const float* bv   = (const float*)d_in[6];
    const float* Wout = (const float*)d_in[7];
    const float* bout = (const float*)d_in[8];
    float* out = (float*)d_out;

    char* wsb = (char*)d_ws;
    _Float16* xb      = (_Float16*)(wsb);                  //  8,388,608
    _Float16* AObf    = (_Float16*)(wsb);                  //  aliases xb (dead after qkv GEMM)
    _Float16* Wqkvb   = (_Float16*)(wsb + 8388608);        //  2,621,440
    _Float16* Woutb   = (_Float16*)(wsb + 11010048);       //  2,097,152
    float*    biasqkv = (float*)   (wsb + 13107200);       //      5,120
    float*    Cqkv    = (float*)   (wsb + 13112320);       // 20,971,520
    _Float16* Lqh     = (_Float16*)(wsb + 34083840);       //  2,097,152
    _Float16* JKf     = (_Float16*)(wsb + 36180992);       //  2,097,152
    _Float16* Vf      = (_Float16*)(wsb + 38278144);       //  8,388,608  (end ~44.5 MB)

    // 1. fp32 -> f16 pack
    convert_kernel<<<dim3(3201), 256, 0, stream>>>(
        x, W1q, W2q, W1k, W2k, Wv, Wout, bv, xb, Wqkvb, Woutb, biasqkv);
    // 2. fused qkv projection: Cqkv = xb @ Wqkvb^T + biasqkv   [4096,1280]
    gemm_f16_mfma<<<dim3(BT / 128, VD / 128), 256, 0, stream>>>(
        xb, Wqkvb, biasqkv, Cqkv, VD, DD);
    // 3. Plucker lines -> Lqh + JKf (fragment-major order)
    exterior_kernel<<<dim3(BT * HH / 256), 256, 0, stream>>>(Cqkv, Lqh, JKf);
    // 4. V -> fragment-major PV order f16
    vtrans_kernel<<<dim3(TT / 64, BB * HH), 256, 0, stream>>>(Cqkv, Vf);
    // 5. causal flash attention (2-wave shared staging, counted vmcnt dbuf)
    flash_mfma_kernel<<<dim3(32 * BB * HH), 128, 0, stream>>>(Lqh, JKf, Vf, AObf);
    // 6. output projection
    gemm_f16_mfma<<<dim3(BT / 128, DD / 128), 256, 0, stream>>>(
        AObf, Woutb, bout, out, DD, DD);
}

// Round 15
// 142.319 us; speedup vs baseline: 1.3266x; 1.3266x over previous
//
#include <hip/hip_runtime.h>
#include <math.h>

#define BB 2
#define TT 2048
#define DD 1024
#define HH 16
#define BT (BB*TT)   // 4096
#define VD 1280      // qkv fused output width

typedef __attribute__((ext_vector_type(4))) _Float16 f16x4;
typedef __attribute__((ext_vector_type(8))) _Float16 f16x8;
typedef __attribute__((ext_vector_type(4))) float f32x4;

__device__ __forceinline__ void gload16(const void* g, void* l) {
    __builtin_amdgcn_global_load_lds((const __attribute__((address_space(1))) void*)g,
                                     (__attribute__((address_space(3))) void*)l, 16, 0, 0);
}

// ---------------- fp32 -> f16 conversion / packing -------------------------
__global__ __launch_bounds__(256) void convert_kernel(
    const float* __restrict__ x,  const float* __restrict__ W1q,
    const float* __restrict__ W2q, const float* __restrict__ W1k,
    const float* __restrict__ W2k, const float* __restrict__ Wv,
    const float* __restrict__ Wout, const float* __restrict__ bv,
    _Float16* __restrict__ xb, _Float16* __restrict__ Wqkvb,
    _Float16* __restrict__ Woutb, float* __restrict__ biasqkv) {
    int c = blockIdx.x * 256 + threadIdx.x;   // chunk of 8 elements
    if (c < 819200) {
        const float* src; _Float16* dst; int off;
        if      (c < 524288) { src = x;    dst = xb;              off = c; }
        else if (c < 532480) { src = W1q;  dst = Wqkvb;           off = c - 524288; }
        else if (c < 540672) { src = W2q;  dst = Wqkvb + 65536;   off = c - 532480; }
        else if (c < 548864) { src = W1k;  dst = Wqkvb + 131072;  off = c - 540672; }
        else if (c < 557056) { src = W2k;  dst = Wqkvb + 196608;  off = c - 548864; }
        else if (c < 688128) { src = Wv;   dst = Wqkvb + 262144;  off = c - 557056; }
        else                 { src = Wout; dst = Woutb;           off = c - 688128; }
        float4 v0 = *(const float4*)(src + (size_t)off * 8);
        float4 v1 = *(const float4*)(src + (size_t)off * 8 + 4);
        f16x8 h;
        h[0] = (_Float16)v0.x; h[1] = (_Float16)v0.y; h[2] = (_Float16)v0.z; h[3] = (_Float16)v0.w;
        h[4] = (_Float16)v1.x; h[5] = (_Float16)v1.y; h[6] = (_Float16)v1.z; h[7] = (_Float16)v1.w;
        *(f16x8*)(dst + (size_t)off * 8) = h;
    } else if (c < 819360) {
        int col0 = (c - 819200) * 8;
        #pragma unroll
        for (int i = 0; i < 8; ++i) {
            int col = col0 + i;
            biasqkv[col] = (col < 256) ? 0.f : bv[col - 256];
        }
    }
}

// ---------------- f16 MFMA GEMM: C[M,N] = A[M,K] @ W[N,K]^T + bias ---------
__global__ __launch_bounds__(256) void gemm_f16_mfma(
    const _Float16* __restrict__ A, const _Float16* __restrict__ W,
    const float* __restrict__ bias, float* __restrict__ C, int N, int K) {
    __shared__ __attribute__((aligned(16))) _Float16 As[128 * 32];
    __shared__ __attribute__((aligned(16))) _Float16 Ws[128 * 32];
    const int tid = threadIdx.x;
    const int w = tid >> 6, lane = tid & 63;
    const int la = lane >> 4, lb = lane & 15;
    const int bm = blockIdx.x * 128, bn = blockIdx.y * 128;
    const int wr = w >> 1, wc = w & 1;

    const int c0 = tid, c1 = tid + 256;
    const int r0 = c0 >> 2, kg0 = (c0 & 3) ^ ((r0 >> 1) & 3);
    const int r1 = c1 >> 2, kg1 = (c1 & 3) ^ ((r1 >> 1) & 3);
    const _Float16* Ag0 = A + (size_t)(bm + r0) * K + kg0 * 8;
    const _Float16* Ag1 = A + (size_t)(bm + r1) * K + kg1 * 8;
    const _Float16* Wg0 = W + (size_t)(bn + r0) * K + kg0 * 8;
    const _Float16* Wg1 = W + (size_t)(bn + r1) * K + kg1 * 8;
    _Float16* Al0 = &As[(w * 64) * 8];
    _Float16* Al1 = &As[(256 + w * 64) * 8];
    _Float16* Wl0 = &Ws[(w * 64) * 8];
    _Float16* Wl1 = &Ws[(256 + w * 64) * 8];

    f32x4 acc[4][4] = {};

    int aoff[4], boff[4];
    #pragma unroll
    for (int t = 0; t < 4; ++t) {
        int ra = wr * 64 + t * 16 + lb;
        aoff[t] = ra * 32 + (la ^ ((ra >> 1) & 3)) * 8;
        int rb = wc * 64 + t * 16 + lb;
        boff[t] = rb * 32 + (la ^ ((rb >> 1) & 3)) * 8;
    }

    for (int k0 = 0; k0 < K; k0 += 32) {
        gload16(Ag0 + k0, Al0);
        gload16(Ag1 + k0, Al1);
        gload16(Wg0 + k0, Wl0);
        gload16(Wg1 + k0, Wl1);
        __syncthreads();
        f16x8 af[4], bf[4];
        #pragma unroll
        for (int t = 0; t < 4; ++t) af[t] = *(const f16x8*)&As[aoff[t]];
        #pragma unroll
        for (int t = 0; t < 4; ++t) bf[t] = *(const f16x8*)&Ws[boff[t]];
        #pragma unroll
        for (int mt = 0; mt < 4; ++mt)
            #pragma unroll
            for (int nt = 0; nt < 4; ++nt)
                acc[mt][nt] = __builtin_amdgcn_mfma_f32_16x16x32_f16(
                    af[mt], bf[nt], acc[mt][nt], 0, 0, 0);
        __syncthreads();
    }

    #pragma unroll
    for (int nt = 0; nt < 4; ++nt) {
        int col = bn + wc * 64 + nt * 16 + lb;
        float bval = bias ? bias[col] : 0.f;
        #pragma unroll
        for (int mt = 0; mt < 4; ++mt) {
            int row = bm + wr * 64 + mt * 16 + la * 4;
            #pragma unroll
            for (int i = 0; i < 4; ++i)
                C[(size_t)(row + i) * N + col] = acc[mt][nt][i] + bval;
        }
    }
}

// ---------------- exterior (Plucker) --------------------------------------
// Lqh: [bh][t][16] f16 (c 6..15 zero).
// JKf: lane-major fragment order [bh][tile(32)][lane(64)][n(4)][4] f16:
//   lane (la,lb) holds K-coeffs c=la*4..+3 of token (tile, n*16+lb).
__device__ __forceinline__ void ext6(const float* a, const float* b, float* L) {
    L[0] = a[0]*b[1] - a[1]*b[0];
    L[1] = a[0]*b[2] - a[2]*b[0];
    L[2] = a[0]*b[3] - a[3]*b[0];
    L[3] = a[1]*b[2] - a[2]*b[1];
    L[4] = a[1]*b[3] - a[3]*b[1];
    L[5] = a[2]*b[3] - a[3]*b[2];
}

__global__ __launch_bounds__(256) void exterior_kernel(const float* __restrict__ Cqkv,
                                                       _Float16* __restrict__ Lqh,
                                                       _Float16* __restrict__ JKf) {
    int idx = blockIdx.x * 256 + threadIdx.x;     // over BT*HH
    if (idx >= BT * HH) return;
    int bt = idx >> 4, h = idx & 15;
    int b = bt >> 11, t = bt & (TT - 1);
    int bh = b * HH + h;
    const float* row = Cqkv + (size_t)bt * VD + h * 4;
    const _Float16 Z = (_Float16)0.f;
    float a[4], bb[4], L[6];
    #pragma unroll
    for (int i = 0; i < 4; ++i) { a[i] = row[i]; bb[i] = row[64 + i]; }
    ext6(a, bb, L);
    float s = 0.f;
    #pragma unroll
    for (int c = 0; c < 6; ++c) s += L[c] * L[c];
    float inv = 1.0f / fmaxf(sqrtf(s), 1e-12f);
    size_t qbase = ((size_t)bh * TT + t) * 16;
    f16x8 lq8 = {(_Float16)(L[0]*inv), (_Float16)(L[1]*inv), (_Float16)(L[2]*inv),
                 (_Float16)(L[3]*inv), (_Float16)(L[4]*inv), (_Float16)(L[5]*inv), Z, Z};
    f16x8 zero8 = {Z, Z, Z, Z, Z, Z, Z, Z};
    *(f16x8*)(Lqh + qbase) = lq8;
    *(f16x8*)(Lqh + qbase + 8) = zero8;

    #pragma unroll
    for (int i = 0; i < 4; ++i) { a[i] = row[128 + i]; bb[i] = row[192 + i]; }
    ext6(a, bb, L);
    s = 0.f;
    #pragma unroll
    for (int c = 0; c < 6; ++c) s += L[c] * L[c];
    const float SCALE = (float)(0.40824829046386307 * 1.4426950408889634); // 6^-0.5 * log2(e)
    inv = SCALE / fmaxf(sqrtf(s), 1e-12f);
    int tile = t >> 6, rr = t & 63, n = rr >> 4, lbt = rr & 15;
    // base = ((bh*32 + tile)*64 + la*16 + lbt)*16 + n*4, la = 0..3
    size_t base = (((size_t)bh * 32 + tile) * 64 + lbt) * 16 + n * 4;
    f16x4 g0 = {(_Float16)( L[5]*inv), (_Float16)(-L[4]*inv),
                (_Float16)( L[3]*inv), (_Float16)( L[2]*inv)};
    f16x4 g1 = {(_Float16)(-L[1]*inv), (_Float16)( L[0]*inv), Z, Z};
    f16x4 z4 = {Z, Z, Z, Z};
    *(f16x4*)&JKf[base]            = g0;   // la=0: c0..3
    *(f16x4*)&JKf[base + 16 * 16]  = g1;   // la=1: c4..7
    *(f16x4*)&JKf[base + 32 * 16]  = z4;   // la=2
    *(f16x4*)&JKf[base + 48 * 16]  = z4;   // la=3
}

// ---------------- V transpose into lane-major PV-fragment order ------------
// Vf: [bh][tile(32)][lane(64)][mn(16)][4] f16 where lane=la*16+lb holds
//     V[t = tile*64 + n*16 + la*4 + j][d = m*16 + lb], mn = m*4+n.
__global__ __launch_bounds__(256) void vtrans_kernel(const float* __restrict__ Cqkv,
                                                     _Float16* __restrict__ Vf) {
    __shared__ float ls[64][65];
    const int bh = blockIdx.y, b = bh >> 4, h = bh & 15;
    const int tile = blockIdx.x;
    const int t0 = tile * 64;
    const int tid = threadIdx.x;
    const int tr = tid >> 2, dg = (tid & 3) * 16;
    const float* src = Cqkv + (size_t)(b * TT + t0 + tr) * VD + 256 + h * 64 + dg;
    #pragma unroll
    for (int j = 0; j < 4; ++j) {
        float4 v = *(const float4*)(src + j * 4);
        ls[tr][dg + j*4 + 0] = v.x;
        ls[tr][dg + j*4 + 1] = v.y;
        ls[tr][dg + j*4 + 2] = v.z;
        ls[tr][dg + j*4 + 3] = v.w;
    }
    __syncthreads();
    _Float16* dst = Vf + ((size_t)bh * 32 + tile) * 4096;
    const int mn = tid & 15, m = mn >> 2, n = mn & 3;
    const int lbl = tid >> 4;          // 0..15
    #pragma unroll
    for (int k = 0; k < 4; ++k) {      // k = la
        int lane = k * 16 + lbl;
        int trow = n * 16 + k * 4;
        int d = m * 16 + lbl;
        f16x4 o = { (_Float16)ls[trow][d],   (_Float16)ls[trow+1][d],
                    (_Float16)ls[trow+2][d], (_Float16)ls[trow+3][d] };
        *(f16x4*)&dst[(size_t)lane * 64 + mn * 4] = o;
    }
}

// ---------------- MFMA flash attention v10: strip-paired, balanced ---------
// 2048 one-wave blocks. Block -> (bh, pair p): wave processes q-strip
// 127-p (heavy) THEN strip p (light): total tiles = (127-p)/4 + p/4 + 2
// ~= 33 for every wave -> perfectly balanced grid, no tail, no LPT.
// Reg-staged tile fragments (lane-major layout, coalesced dwordx4 loads);
// p = exp2(s') directly (scores bounded by 6^-0.5, no online max).
__global__ __launch_bounds__(64) void flash_mfma_kernel(
    const _Float16* __restrict__ Lqh, const _Float16* __restrict__ JKf,
    const _Float16* __restrict__ Vf, _Float16* __restrict__ O) {
    const int id = blockIdx.x;                       // 0..2047
    const int bh = (id & 7) * 4 + ((id >> 3) & 3);   // 4 bh per XCD slot
    const int p = id >> 5;                           // pair index 0..63
    const int b = bh >> 4, h = bh & 15;
    const int lane = threadIdx.x;                    // 0..63
    const int la = lane >> 4, lb = lane & 15;

    const _Float16* jsrc = JKf + ((size_t)bh * 32) * 1024 + lane * 16;
    const _Float16* vsrc = Vf + ((size_t)bh * 32) * 4096 + lane * 64;

    auto run_strip = [&](int strip) {
        const int qw = strip * 16;                   // wave's 16 q rows
        const int ql = qw + lb;
        // B-frag: blq[j] = Lq[q=qw+lb][k=la*4+j]; k>=6 stored zero
        f16x4 blq = *(const f16x4*)(Lqh + ((size_t)bh * TT + qw + lb) * 16 + la * 4);
        f32x4 acc[4] = {};
        f32x4 lsv = {0.f, 0.f, 0.f, 0.f};
        const int nt = (qw >> 6) + 1;                // tiles this strip needs

        for (int t = 0; t < nt; ++t) {
            // load tile fragments straight to VGPRs (lane-contiguous)
            f16x8 j0, j1, v[8];
            {
                const _Float16* jp = jsrc + (size_t)t * 1024;
                j0 = *(const f16x8*)(jp);
                j1 = *(const f16x8*)(jp + 8);
                const _Float16* vp = vsrc + (size_t)t * 4096;
                #pragma unroll
                for (int i = 0; i < 8; ++i) v[i] = *(const f16x8*)(vp + i * 8);
            }
            __builtin_amdgcn_sched_barrier(0);
            const int kt = t * 64;
            #pragma unroll
            for (int n = 0; n < 4; ++n) {
                const int kbase = kt + n * 16;
                if (kbase > qw + 15) break;          // wave-uniform
                const f16x8 js = (n < 2) ? j0 : j1;
                f16x4 ajk = (n & 1) ? __builtin_shufflevector(js, js, 4, 5, 6, 7)
                                    : __builtin_shufflevector(js, js, 0, 1, 2, 3);
                f32x4 st = __builtin_amdgcn_mfma_f32_16x16x16f16(
                    ajk, blq, (f32x4){0.f, 0.f, 0.f, 0.f}, 0, 0, 0);
                const bool needm = (kbase + 15 > qw);
                f16x4 pt;
                #pragma unroll
                for (int i = 0; i < 4; ++i) {
                    float pp = exp2f(st[i]);
                    if (needm) {
                        int key = kbase + la * 4 + i;
                        pp = (key <= ql) ? pp : 0.f;
                    }
                    lsv[i] += pp;
                    pt[i] = (_Float16)pp;
                }
                #pragma unroll
                for (int m = 0; m < 4; ++m) {
                    const int mn = m * 4 + n;
                    const f16x8 vv = v[mn >> 1];
                    f16x4 av = (mn & 1) ? __builtin_shufflevector(vv, vv, 4, 5, 6, 7)
                                        : __builtin_shufflevector(vv, vv, 0, 1, 2, 3);
                    acc[m] = __builtin_amdgcn_mfma_f32_16x16x16f16(av, pt, acc[m], 0, 0, 0);
                }
            }
        }

        // reduce lsum across the 4 la-groups holding the same q column
        float lsum = lsv[0] + lsv[1] + lsv[2] + lsv[3];
        lsum += __shfl_xor(lsum, 16);
        lsum += __shfl_xor(lsum, 32);
        const float inv = 1.f / lsum;
        #pragma unroll
        for (int m = 0; m < 4; ++m) {
            f16x4 o = { (_Float16)(acc[m][0] * inv), (_Float16)(acc[m][1] * inv),
                        (_Float16)(acc[m][2] * inv), (_Float16)(acc[m][3] * inv) };
            *(f16x4*)&O[(size_t)(b * TT + ql) * DD + h * 64 + m * 16 + la * 4] = o;
        }
    };

    run_strip(127 - p);   // heavy half of the pair
    run_strip(p);         // light half
}

extern "C" void kernel_launch(void* const* d_in, const int* in_sizes, int n_in,
                              void* d_out, int out_size, void* d_ws, size_t ws_size,
                              hipStream_t stream) {
    const float* x    = (const float*)d_in[0];
    const float* W1q  = (const float*)d_in[1];
    const float* W2q  = (const float*)d_in[2];
    const float* W1k  = (const float*)d_in[3];
    const float* W2k  = (const float*)d_in[4];
    const float* Wv   = (const float*)d_in[5];
    const float* bv   = (const float*)d_in[6];
    const float* Wout = (const float*)d_in[7];
    const float* bout = (const float*)d_in[8];
    float* out = (float*)d_out;

    char* wsb = (char*)d_ws;
    _Float16* xb      = (_Float16*)(wsb);                  //  8,388,608
    _Float16* AObf    = (_Float16*)(wsb);                  //  aliases xb (dead after qkv GEMM)
    _Float16* Wqkvb   = (_Float16*)(wsb + 8388608);        //  2,621,440
    _Float16* Woutb   = (_Float16*)(wsb + 11010048);       //  2,097,152
    float*    biasqkv = (float*)   (wsb + 13107200);       //      5,120
    float*    Cqkv    = (float*)   (wsb + 13112320);       // 20,971,520
    _Float16* Lqh     = (_Float16*)(wsb + 34083840);       //  2,097,152
    _Float16* JKf     = (_Float16*)(wsb + 36180992);       //  2,097,152
    _Float16* Vf      = (_Float16*)(wsb + 38278144);       //  8,388,608  (end ~44.5 MB)

    // 1. fp32 -> f16 pack
    convert_kernel<<<dim3(3201), 256, 0, stream>>>(
        x, W1q, W2q, W1k, W2k, Wv, Wout, bv, xb, Wqkvb, Woutb, biasqkv);
    // 2. fused qkv projection: Cqkv = xb @ Wqkvb^T + biasqkv   [4096,1280]
    gemm_f16_mfma<<<dim3(BT / 128, VD / 128), 256, 0, stream>>>(
        xb, Wqkvb, biasqkv, Cqkv, VD, DD);
    // 3. Plucker lines -> Lqh + JKf (lane-major fragment order)
    exterior_kernel<<<dim3(BT * HH / 256), 256, 0, stream>>>(Cqkv, Lqh, JKf);
    // 4. V -> lane-major PV-fragment order f16
    vtrans_kernel<<<dim3(TT / 64, BB * HH), 256, 0, stream>>>(Cqkv, Vf);
    // 5. causal flash attention (strip-paired balanced, reg-staged)
    flash_mfma_kernel<<<dim3(2048), 64, 0, stream>>>(Lqh, JKf, Vf, AObf);
    // 6. output projection
    gemm_f16_mfma<<<dim3(BT / 128, DD / 128), 256, 0, stream>>>(
        AObf, Woutb, bout, out, DD, DD);
}

// Round 17
// 107.208 us; speedup vs baseline: 1.7610x; 1.3275x over previous
//
#include <hip/hip_runtime.h>
#include <math.h>

#define BB 2
#define TT 2048
#define DD 1024
#define HH 16
#define BT (BB*TT)   // 4096
#define VD 1280      // qkv fused output width

typedef __attribute__((ext_vector_type(4))) _Float16 f16x4;
typedef __attribute__((ext_vector_type(8))) _Float16 f16x8;
typedef __attribute__((ext_vector_type(4))) float f32x4;
typedef __attribute__((ext_vector_type(16))) float f32x16;

__device__ __forceinline__ void gload16(const void* g, void* l) {
    __builtin_amdgcn_global_load_lds((const __attribute__((address_space(1))) void*)g,
                                     (__attribute__((address_space(3))) void*)l, 16, 0, 0);
}

// ---------------- fp32 -> f16 conversion / packing -------------------------
__global__ __launch_bounds__(256) void convert_kernel(
    const float* __restrict__ x,  const float* __restrict__ W1q,
    const float* __restrict__ W2q, const float* __restrict__ W1k,
    const float* __restrict__ W2k, const float* __restrict__ Wv,
    const float* __restrict__ Wout, const float* __restrict__ bv,
    _Float16* __restrict__ xb, _Float16* __restrict__ Wqkvb,
    _Float16* __restrict__ Woutb, float* __restrict__ biasqkv) {
    int c = blockIdx.x * 256 + threadIdx.x;   // chunk of 8 elements
    if (c < 819200) {
        const float* src; _Float16* dst; int off;
        if      (c < 524288) { src = x;    dst = xb;              off = c; }
        else if (c < 532480) { src = W1q;  dst = Wqkvb;           off = c - 524288; }
        else if (c < 540672) { src = W2q;  dst = Wqkvb + 65536;   off = c - 532480; }
        else if (c < 548864) { src = W1k;  dst = Wqkvb + 131072;  off = c - 540672; }
        else if (c < 557056) { src = W2k;  dst = Wqkvb + 196608;  off = c - 548864; }
        else if (c < 688128) { src = Wv;   dst = Wqkvb + 262144;  off = c - 557056; }
        else                 { src = Wout; dst = Woutb;           off = c - 688128; }
        float4 v0 = *(const float4*)(src + (size_t)off * 8);
        float4 v1 = *(const float4*)(src + (size_t)off * 8 + 4);
        f16x8 h;
        h[0] = (_Float16)v0.x; h[1] = (_Float16)v0.y; h[2] = (_Float16)v0.z; h[3] = (_Float16)v0.w;
        h[4] = (_Float16)v1.x; h[5] = (_Float16)v1.y; h[6] = (_Float16)v1.z; h[7] = (_Float16)v1.w;
        *(f16x8*)(dst + (size_t)off * 8) = h;
    } else if (c < 819360) {
        int col0 = (c - 819200) * 8;
        #pragma unroll
        for (int i = 0; i < 8; ++i) {
            int col = col0 + i;
            biasqkv[col] = (col < 256) ? 0.f : bv[col - 256];
        }
    }
}

// ---------------- f16 MFMA GEMM: C[M,N] = A[M,K] @ W[N,K]^T + bias ---------
__global__ __launch_bounds__(256) void gemm_f16_mfma(
    const _Float16* __restrict__ A, const _Float16* __restrict__ W,
    const float* __restrict__ bias, float* __restrict__ C, int N, int K) {
    __shared__ __attribute__((aligned(16))) _Float16 As[128 * 32];
    __shared__ __attribute__((aligned(16))) _Float16 Ws[128 * 32];
    const int tid = threadIdx.x;
    const int w = tid >> 6, lane = tid & 63;
    const int la = lane >> 4, lb = lane & 15;
    const int bm = blockIdx.x * 128, bn = blockIdx.y * 128;
    const int wr = w >> 1, wc = w & 1;

    const int c0 = tid, c1 = tid + 256;
    const int r0 = c0 >> 2, kg0 = (c0 & 3) ^ ((r0 >> 1) & 3);
    const int r1 = c1 >> 2, kg1 = (c1 & 3) ^ ((r1 >> 1) & 3);
    const _Float16* Ag0 = A + (size_t)(bm + r0) * K + kg0 * 8;
    const _Float16* Ag1 = A + (size_t)(bm + r1) * K + kg1 * 8;
    const _Float16* Wg0 = W + (size_t)(bn + r0) * K + kg0 * 8;
    const _Float16* Wg1 = W + (size_t)(bn + r1) * K + kg1 * 8;
    _Float16* Al0 = &As[(w * 64) * 8];
    _Float16* Al1 = &As[(256 + w * 64) * 8];
    _Float16* Wl0 = &Ws[(w * 64) * 8];
    _Float16* Wl1 = &Ws[(256 + w * 64) * 8];

    f32x4 acc[4][4] = {};

    int aoff[4], boff[4];
    #pragma unroll
    for (int t = 0; t < 4; ++t) {
        int ra = wr * 64 + t * 16 + lb;
        aoff[t] = ra * 32 + (la ^ ((ra >> 1) & 3)) * 8;
        int rb = wc * 64 + t * 16 + lb;
        boff[t] = rb * 32 + (la ^ ((rb >> 1) & 3)) * 8;
    }

    for (int k0 = 0; k0 < K; k0 += 32) {
        gload16(Ag0 + k0, Al0);
        gload16(Ag1 + k0, Al1);
        gload16(Wg0 + k0, Wl0);
        gload16(Wg1 + k0, Wl1);
        __syncthreads();
        f16x8 af[4], bf[4];
        #pragma unroll
        for (int t = 0; t < 4; ++t) af[t] = *(const f16x8*)&As[aoff[t]];
        #pragma unroll
        for (int t = 0; t < 4; ++t) bf[t] = *(const f16x8*)&Ws[boff[t]];
        #pragma unroll
        for (int mt = 0; mt < 4; ++mt)
            #pragma unroll
            for (int nt = 0; nt < 4; ++nt)
                acc[mt][nt] = __builtin_amdgcn_mfma_f32_16x16x32_f16(
                    af[mt], bf[nt], acc[mt][nt], 0, 0, 0);
        __syncthreads();
    }

    #pragma unroll
    for (int nt = 0; nt < 4; ++nt) {
        int col = bn + wc * 64 + nt * 16 + lb;
        float bval = bias ? bias[col] : 0.f;
        #pragma unroll
        for (int mt = 0; mt < 4; ++mt) {
            int row = bm + wr * 64 + mt * 16 + la * 4;
            #pragma unroll
            for (int i = 0; i < 4; ++i)
                C[(size_t)(row + i) * N + col] = acc[mt][nt][i] + bval;
        }
    }
}

// ---------------- exterior (Plucker) --------------------------------------
// Lqh: [bh][t][16] f16 (slots 6..15 zero) — 32x32x16 B-operand (k-padded).
// JKf: [bh][tile(32)][key(64)][16] f16 (slots 6..15 zero) — 32x32x16
//      A-operand: lane (lh,lq) reads key 32n+lq, slots lh*8..+7.
__device__ __forceinline__ void ext6(const float* a, const float* b, float* L) {
    L[0] = a[0]*b[1] - a[1]*b[0];
    L[1] = a[0]*b[2] - a[2]*b[0];
    L[2] = a[0]*b[3] - a[3]*b[0];
    L[3] = a[1]*b[2] - a[2]*b[1];
    L[4] = a[1]*b[3] - a[3]*b[1];
    L[5] = a[2]*b[3] - a[3]*b[2];
}

__global__ __launch_bounds__(256) void exterior_kernel(const float* __restrict__ Cqkv,
                                                       _Float16* __restrict__ Lqh,
                                                       _Float16* __restrict__ JKf) {
    int idx = blockIdx.x * 256 + threadIdx.x;     // over BT*HH
    if (idx >= BT * HH) return;
    int bt = idx >> 4, h = idx & 15;
    int b = bt >> 11, t = bt & (TT - 1);
    int bh = b * HH + h;
    const float* row = Cqkv + (size_t)bt * VD + h * 4;
    const _Float16 Z = (_Float16)0.f;
    f16x8 zero8 = {Z, Z, Z, Z, Z, Z, Z, Z};
    float a[4], bb[4], L[6];
    #pragma unroll
    for (int i = 0; i < 4; ++i) { a[i] = row[i]; bb[i] = row[64 + i]; }
    ext6(a, bb, L);
    float s = 0.f;
    #pragma unroll
    for (int c = 0; c < 6; ++c) s += L[c] * L[c];
    float inv = 1.0f / fmaxf(sqrtf(s), 1e-12f);
    size_t qbase = ((size_t)bh * TT + t) * 16;
    f16x8 lq8 = {(_Float16)(L[0]*inv), (_Float16)(L[1]*inv), (_Float16)(L[2]*inv),
                 (_Float16)(L[3]*inv), (_Float16)(L[4]*inv), (_Float16)(L[5]*inv), Z, Z};
    *(f16x8*)(Lqh + qbase) = lq8;
    *(f16x8*)(Lqh + qbase + 8) = zero8;

    #pragma unroll
    for (int i = 0; i < 4; ++i) { a[i] = row[128 + i]; bb[i] = row[192 + i]; }
    ext6(a, bb, L);
    s = 0.f;
    #pragma unroll
    for (int c = 0; c < 6; ++c) s += L[c] * L[c];
    const float SCALE = (float)(0.40824829046386307 * 1.4426950408889634); // 6^-0.5 * log2(e)
    inv = SCALE / fmaxf(sqrtf(s), 1e-12f);
    int tile = t >> 6, ko = t & 63;
    size_t base = (((size_t)bh * 32 + tile) * 64 + ko) * 16;
    f16x8 jk8 = {(_Float16)( L[5]*inv), (_Float16)(-L[4]*inv), (_Float16)(L[3]*inv),
                 (_Float16)( L[2]*inv), (_Float16)(-L[1]*inv), (_Float16)(L[0]*inv), Z, Z};
    *(f16x8*)&JKf[base] = jk8;
    *(f16x8*)&JKf[base + 8] = zero8;
}

// ---------------- V -> 32x32x16 PV A-fragment order ------------------------
// Vf: [bh][tile(32)][frag(8)][lane(64)][8] f16, frag = m*4 + n*2 + g.
// lane (lh,lq), elem j holds V[t0 + 32n + 16g + 4lh + (j&3) + 8*(j>>2)]
//                            [d = 32m + lq]
// — exactly the score-MFMA's NATIVE C/D key layout (no cross-lane redist).
__global__ __launch_bounds__(256) void vtrans_kernel(const float* __restrict__ Cqkv,
                                                     _Float16* __restrict__ Vf) {
    __shared__ float ls[64][65];
    const int bh = blockIdx.y, b = bh >> 4, h = bh & 15;
    const int tile = blockIdx.x;
    const int t0 = tile * 64;
    const int tid = threadIdx.x;
    const int tr = tid >> 2, dg = (tid & 3) * 16;
    const float* src = Cqkv + (size_t)(b * TT + t0 + tr) * VD + 256 + h * 64 + dg;
    #pragma unroll
    for (int j = 0; j < 4; ++j) {
        float4 v = *(const float4*)(src + j * 4);
        ls[tr][dg + j*4 + 0] = v.x;
        ls[tr][dg + j*4 + 1] = v.y;
        ls[tr][dg + j*4 + 2] = v.z;
        ls[tr][dg + j*4 + 3] = v.w;
    }
    __syncthreads();
    _Float16* dst = Vf + ((size_t)bh * 32 + tile) * 4096;
    #pragma unroll
    for (int k = 0; k < 2; ++k) {
        int u = k * 256 + tid;                 // frag-lane unit 0..511
        int f = u >> 6, lane = u & 63;
        int m = f >> 2, n = (f >> 1) & 1, g = f & 1;
        int lh = lane >> 5, lq = lane & 31;
        int rbase = 32 * n + 16 * g + 4 * lh;  // native P layout order
        int d = 32 * m + lq;
        f16x8 o;
        #pragma unroll
        for (int j = 0; j < 8; ++j)
            o[j] = (_Float16)ls[rbase + (j & 3) + 8 * (j >> 2)][d];
        *(f16x8*)&dst[(size_t)(f * 64 + lane) * 8] = o;
    }
}

// ---------------- MFMA flash attention v12: 32x32x16, native-P PV ----------
// 2048 one-wave blocks; wave owns 32 q (strip s), tiles of 64 keys.
// S^T via mfma_32x32x16 (A=JK keys, B=Lq^T; k 6..15 zero from storage).
// PV B-operand IS the score output cast to f16 in-place: bg0[r]=P(pr[r]),
// bg1[r]=P(pr[r+8]) — keys {4lh+0..3,8..11}(+16g,+32n). V pre-arranged by
// vtrans into that SAME native order -> zero cross-lane redistribution.
// p = exp2(s') directly (scores bounded by 6^-0.5, no online max).
__global__ __launch_bounds__(64, 2) void flash_mfma_kernel(
    const _Float16* __restrict__ Lqh, const _Float16* __restrict__ JKf,
    const _Float16* __restrict__ Vf, _Float16* __restrict__ O) {
    const int id = blockIdx.x;                       // 0..2047
    const int bh = (id & 7) * 4 + ((id >> 3) & 3);   // 4 bh per XCD slot
    const int s = 63 - (id >> 5);                    // strip, heavy first
    const int b = bh >> 4, h = bh & 15;
    const int lane = threadIdx.x;                    // 0..63
    const int lh = lane >> 5, lq = lane & 31;
    const int qw = s * 32;

    const _Float16* jsrc = JKf + (size_t)bh * 32768 + lq * 16 + lh * 8;
    const _Float16* vsrc = Vf + (size_t)bh * 131072 + lane * 8;
    f16x8 blq = *(const f16x8*)(Lqh + ((size_t)bh * TT + qw + lq) * 16 + lh * 8);

    f32x16 acc0 = {}, acc1 = {};
    float lsA = 0.f, lsB = 0.f;
    const int nt = (s >> 1) + 1;

#define PROC_N(STV, NN, MASKED) { \
    float pr[16]; \
    int limh = 0; \
    if (MASKED) limh = qw + lq - 4 * lh - kt - 32 * (NN); \
    _Pragma("unroll") \
    for (int r = 0; r < 16; ++r) { \
        float e = exp2f((STV)[r]); \
        if (MASKED) { const int kc = (r & 3) + 8 * (r >> 2); \
                      e = (kc <= limh) ? e : 0.f; } \
        pr[r] = e; \
        if (r & 1) lsB += e; else lsA += e; \
    } \
    _Pragma("unroll") \
    for (int r = 0; r < 8; ++r) { \
        bg0[r] = (_Float16)pr[r]; \
        bg1[r] = (_Float16)pr[r + 8]; \
    } }

#define TILE(T, MASKED) { \
    const int kt = (T) * 64; \
    const _Float16* jp = jsrc + (size_t)(T) * 1024; \
    const _Float16* vp = vsrc + (size_t)(T) * 4096; \
    f16x8 j0 = *(const f16x8*)(jp); \
    f16x8 j1 = *(const f16x8*)(jp + 512); \
    f16x8 vf0 = *(const f16x8*)(vp); \
    f16x8 vf1 = *(const f16x8*)(vp + 512); \
    f16x8 vf2 = *(const f16x8*)(vp + 1024); \
    f16x8 vf3 = *(const f16x8*)(vp + 1536); \
    f16x8 vf4 = *(const f16x8*)(vp + 2048); \
    f16x8 vf5 = *(const f16x8*)(vp + 2560); \
    f16x8 vf6 = *(const f16x8*)(vp + 3072); \
    f16x8 vf7 = *(const f16x8*)(vp + 3584); \
    __builtin_amdgcn_sched_barrier(0); \
    const f32x16 z16 = {}; \
    f16x8 bg0, bg1; \
    f32x16 st = __builtin_amdgcn_mfma_f32_32x32x16_f16(j0, blq, z16, 0, 0, 0); \
    PROC_N(st, 0, MASKED); \
    acc0 = __builtin_amdgcn_mfma_f32_32x32x16_f16(vf0, bg0, acc0, 0, 0, 0); \
    acc0 = __builtin_amdgcn_mfma_f32_32x32x16_f16(vf1, bg1, acc0, 0, 0, 0); \
    acc1 = __builtin_amdgcn_mfma_f32_32x32x16_f16(vf4, bg0, acc1, 0, 0, 0); \
    acc1 = __builtin_amdgcn_mfma_f32_32x32x16_f16(vf5, bg1, acc1, 0, 0, 0); \
    st = __builtin_amdgcn_mfma_f32_32x32x16_f16(j1, blq, z16, 0, 0, 0); \
    PROC_N(st, 1, MASKED); \
    acc0 = __builtin_amdgcn_mfma_f32_32x32x16_f16(vf2, bg0, acc0, 0, 0, 0); \
    acc0 = __builtin_amdgcn_mfma_f32_32x32x16_f16(vf3, bg1, acc0, 0, 0, 0); \
    acc1 = __builtin_amdgcn_mfma_f32_32x32x16_f16(vf6, bg0, acc1, 0, 0, 0); \
    acc1 = __builtin_amdgcn_mfma_f32_32x32x16_f16(vf7, bg1, acc1, 0, 0, 0); }

    for (int t = 0; t < nt - 1; ++t) TILE(t, false);
    TILE(nt - 1, true);
#undef TILE
#undef PROC_N

    float lsum = lsA + lsB;
    lsum += __shfl_xor(lsum, 32);
    const float inv = 1.f / lsum;
    _Float16* op = O + (size_t)(b * TT + qw + lq) * DD + h * 64 + 4 * lh;
    #pragma unroll
    for (int m = 0; m < 2; ++m) {
        #pragma unroll
        for (int rq = 0; rq < 4; ++rq) {
            const f32x16& a = m ? acc1 : acc0;
            f16x4 o = { (_Float16)(a[4*rq+0] * inv), (_Float16)(a[4*rq+1] * inv),
                        (_Float16)(a[4*rq+2] * inv), (_Float16)(a[4*rq+3] * inv) };
            *(f16x4*)(op + 32 * m + 8 * rq) = o;
        }
    }
}

extern "C" void kernel_launch(void* const* d_in, const int* in_sizes, int n_in,
                              void* d_out, int out_size, void* d_ws, size_t ws_size,
                              hipStream_t stream) {
    const float* x    = (const float*)d_in[0];
    const float* W1q  = (const float*)d_in[1];
    const float* W2q  = (const float*)d_in[2];
    const float* W1k  = (const float*)d_in[3];
    const float* W2k  = (const float*)d_in[4];
    const float* Wv   = (const float*)d_in[5];
    const float* bv   = (const float*)d_in[6];
    const float* Wout = (const float*)d_in[7];
    const float* bout = (const float*)d_in[8];
    float* out = (float*)d_out;

    char* wsb = (char*)d_ws;
    _Float16* xb      = (_Float16*)(wsb);                  //  8,388,608
    _Float16* AObf    = (_Float16*)(wsb);                  //  aliases xb (dead after qkv GEMM)
    _Float16* Wqkvb   = (_Float16*)(wsb + 8388608);        //  2,621,440
    _Float16* Woutb   = (_Float16*)(wsb + 11010048);       //  2,097,152
    float*    biasqkv = (float*)   (wsb + 13107200);       //      5,120
    float*    Cqkv    = (float*)   (wsb + 13112320);       // 20,971,520
    _Float16* Lqh     = (_Float16*)(wsb + 34083840);       //  2,097,152
    _Float16* JKf     = (_Float16*)(wsb + 36180992);       //  2,097,152
    _Float16* Vf      = (_Float16*)(wsb + 38278144);       //  8,388,608  (end ~44.5 MB)

    // 1. fp32 -> f16 pack
    convert_kernel<<<dim3(3201), 256, 0, stream>>>(
        x, W1q, W2q, W1k, W2k, Wv, Wout, bv, xb, Wqkvb, Woutb, biasqkv);
    // 2. fused qkv projection: Cqkv = xb @ Wqkvb^T + biasqkv   [4096,1280]
    gemm_f16_mfma<<<dim3(BT / 128, VD / 128), 256, 0, stream>>>(
        xb, Wqkvb, biasqkv, Cqkv, VD, DD);
    // 3. Plucker lines -> Lqh + JKf (32x32 operand order, zero-padded k)
    exterior_kernel<<<dim3(BT * HH / 256), 256, 0, stream>>>(Cqkv, Lqh, JKf);
    // 4. V -> 32x32 PV fragment order (native score-output key layout)
    vtrans_kernel<<<dim3(TT / 64, BB * HH), 256, 0, stream>>>(Cqkv, Vf);
    // 5. causal flash attention (32x32x16 MFMA, native-P PV)
    flash_mfma_kernel<<<dim3(2048), 64, 0, stream>>>(Lqh, JKf, Vf, AObf);
    // 6. output projection
    gemm_f16_mfma<<<dim3(BT / 128, DD / 128), 256, 0, stream>>>(
        AObf, Woutb, bout, out, DD, DD);
}